// Round 13
// baseline (157.660 us; speedup 1.0000x reference)
//
#include <hip/hip_runtime.h>
#include <math.h>

typedef unsigned short u16;
typedef __attribute__((ext_vector_type(8))) short short8;
typedef __attribute__((ext_vector_type(4))) float floatx4;
typedef __attribute__((ext_vector_type(2))) unsigned int uint2v;
typedef __attribute__((ext_vector_type(4))) unsigned int uint4v;

#define SEQ 1024
#define CDIM 384
#define NH 8
#define DH 48
#define DP 64   // padded head dim for Q/K storage
#define NB 8

__device__ __forceinline__ u16 f2bf(float f){
  unsigned int u; __builtin_memcpy(&u, &f, 4);
  u = (u + 0x7fffu + ((u >> 16) & 1u)) >> 16;
  return (u16)u;
}
// pack two fp32 -> two bf16 (RTNE) in one u32: low16 = a, high16 = b
__device__ __forceinline__ unsigned packbf(float a, float b){
  unsigned ua, ub; __builtin_memcpy(&ua, &a, 4); __builtin_memcpy(&ub, &b, 4);
  ua += 0x7fffu + ((ua >> 16) & 1u);
  ub += 0x7fffu + ((ub >> 16) & 1u);
  return __builtin_amdgcn_perm(ub, ua, 0x07060302);
}
__device__ __forceinline__ void async16(const u16* g, u16* l){
  __builtin_amdgcn_global_load_lds((const __attribute__((address_space(1))) void*)g,
                                   (__attribute__((address_space(3))) void*)l, 16, 0, 0);
}

// ---------------- Kernel 1: QKV GEMM, fused x-transpose + W conversion ----------------
// qkv[o][s] = W[o][c] (fp32) * x[c][s] (fp32); 128x64 tile, BK=64; grid (16, 9, 8)
// A: W rows staged fp32->bf16 with chunk^(row&7) XOR layout (read side same as before)
// B: x tile transposed in LDS to [s][c] stride 72, fp32->bf16
__global__ __launch_bounds__(256) void qkv_kernel(const float* __restrict__ W,
                                                  const float* __restrict__ x,
                                                  u16* __restrict__ qws,
                                                  u16* __restrict__ kws,
                                                  u16* __restrict__ vws){
  __shared__ u16 ldsA[128 * 64];   // 16 KB
  __shared__ u16 ldsB[64 * 72];    // 9 KB, [s][c] padded
  const int t = threadIdx.x;
  const int w = t >> 6, l = t & 63;
  const int quad = l >> 4, li = l & 15;
  const int n0 = blockIdx.x * 64;
  const int m0 = blockIdx.y * 128;
  const int b  = blockIdx.z;

  floatx4 acc[2][4];
#pragma unroll
  for (int i = 0; i < 2; i++)
#pragma unroll
    for (int j = 0; j < 4; j++) acc[i][j] = (floatx4)0.0f;

  const float* xb = x + (size_t)b * CDIM * SEQ;
  const int swz = li & 7;

  // staging thread roles
  const int orow = t >> 1, ohalf = (t & 1) * 32;   // A: row m0+orow, c-range ohalf..+32
  const int cpair = t >> 3, si = t & 7;            // B: c = cpair*2 (+2 rows), s = si*8 (+8)

  // ---- register preload for kk = 0 ----
  float4 areg[8];
  float4 b00, b01, b10, b11;
  {
    const float* ar = W + (size_t)(m0 + orow) * CDIM + ohalf;
#pragma unroll
    for (int j = 0; j < 8; j++) areg[j] = *(const float4*)(ar + j * 4);
    const float* r0 = xb + (size_t)(cpair * 2) * SEQ + n0 + si * 8;
    b00 = *(const float4*)r0;        b01 = *(const float4*)(r0 + 4);
    b10 = *(const float4*)(r0+SEQ);  b11 = *(const float4*)(r0 + SEQ + 4);
  }

  for (int kk = 0; kk < CDIM; kk += 64){
    __syncthreads();   // previous iteration's fragment reads done
    // ---- A tile: regs -> LDS (bf16, XOR-chunk layout) ----
#pragma unroll
    for (int j = 0; j < 4; j++){
      uint4v v;
      v[0] = packbf(areg[2*j].x,   areg[2*j].y);
      v[1] = packbf(areg[2*j].z,   areg[2*j].w);
      v[2] = packbf(areg[2*j+1].x, areg[2*j+1].y);
      v[3] = packbf(areg[2*j+1].z, areg[2*j+1].w);
      const int chunk = (((t & 1) * 4 + j) ^ (orow & 7));
      *(uint4v*)&ldsA[orow * 64 + chunk * 8] = v;
    }
    // ---- B tile: regs -> LDS transposed [s][c] (bf16) ----
    {
      const float ca[8] = {b00.x,b00.y,b00.z,b00.w, b01.x,b01.y,b01.z,b01.w};
      const float cb[8] = {b10.x,b10.y,b10.z,b10.w, b11.x,b11.y,b11.z,b11.w};
#pragma unroll
      for (int j = 0; j < 8; j++)
        *(unsigned*)&ldsB[(si * 8 + j) * 72 + cpair * 2] = packbf(ca[j], cb[j]);
    }
    __syncthreads();   // LDS writes visible

    // ---- prefetch next iteration's registers (overlaps compute) ----
    if (kk + 64 < CDIM){
      const float* ar = W + (size_t)(m0 + orow) * CDIM + kk + 64 + ohalf;
#pragma unroll
      for (int j = 0; j < 8; j++) areg[j] = *(const float4*)(ar + j * 4);
      const float* r0 = xb + (size_t)(kk + 64 + cpair * 2) * SEQ + n0 + si * 8;
      b00 = *(const float4*)r0;        b01 = *(const float4*)(r0 + 4);
      b10 = *(const float4*)(r0+SEQ);  b11 = *(const float4*)(r0 + SEQ + 4);
    }

    // ---- compute ----
#pragma unroll
    for (int kc = 0; kc < 2; kc++){
      const int rc = ((kc * 4 + quad) ^ swz) << 3;
      short8 af[2], bf[4];
#pragma unroll
      for (int i = 0; i < 2; i++)
        af[i] = *(const short8*)&ldsA[(w * 32 + i * 16 + li) * 64 + rc];
#pragma unroll
      for (int j = 0; j < 4; j++)
        bf[j] = *(const short8*)&ldsB[(j * 16 + li) * 72 + kc * 32 + quad * 8];
#pragma unroll
      for (int i = 0; i < 2; i++)
#pragma unroll
        for (int j = 0; j < 4; j++)
          acc[i][j] = __builtin_amdgcn_mfma_f32_16x16x32_bf16(af[i], bf[j], acc[i][j], 0, 0, 0);
    }
  }

  const float qs = 0.14433756729740643f * 1.4426950408889634f; // d^-0.5 * log2(e)
  const uint2v z2 = (uint2v)0u;
#pragma unroll
  for (int i = 0; i < 2; i++){
    const int obase = m0 + w * 32 + i * 16 + quad * 4;
    const int which = obase / CDIM;
    const int rem = obase - which * CDIM;
    const int h = rem / DH;
    const int dd = rem - h * DH;
    const int pair = b * NH + h;
#pragma unroll
    for (int j = 0; j < 4; j++){
      const int s = n0 + j * 16 + li;
      floatx4 v = acc[i][j];
      if (which == 0){
        uint2v pk; pk[0] = packbf(v[0] * qs, v[1] * qs); pk[1] = packbf(v[2] * qs, v[3] * qs);
        *(uint2v*)&qws[((size_t)pair * SEQ + s) * DP + dd] = pk;
        if ((dd & 48) == 32)
          *(uint2v*)&qws[((size_t)pair * SEQ + s) * DP + dd + 16] = z2;
      } else if (which == 1){
        uint2v pk; pk[0] = packbf(v[0], v[1]); pk[1] = packbf(v[2], v[3]);
        *(uint2v*)&kws[((size_t)pair * SEQ + s) * DP + dd] = pk;
        if ((dd & 48) == 32)
          *(uint2v*)&kws[((size_t)pair * SEQ + s) * DP + dd + 16] = z2;
      } else {
#pragma unroll
        for (int r = 0; r < 4; r++)
          vws[((size_t)pair * DH + dd + r) * SEQ + s] = f2bf(v[r]);
      }
    }
  }
}

// ---------------- Kernel 2: flash attention, 16 q/wave, 4 blocks/CU ----------------
// 1-D grid of 1024: pair = id & 63, qb = id >> 6  =>  id % 8 == pair % 8 (XCD sharing)
__global__ __launch_bounds__(256) void attn_kernel(const u16* __restrict__ qws,
                                                   const u16* __restrict__ kws,
                                                   const u16* __restrict__ vws,
                                                   u16* __restrict__ aT){
  __shared__ u16 ldsK[2][64 * 64];
  __shared__ u16 ldsV[2][48 * 64];
  __shared__ u16 ldsP[64 * 72];

  const int t = threadIdx.x;
  const int w = t >> 6, l = t & 63;
  const int quad = l >> 4, li = l & 15;
  const int id = blockIdx.x;
  const int pair = id & 63;
  const int qb = id >> 6;
  const int b = pair >> 3, h = pair & 7;
  const int qbase = qb * 64 + w * 16;
  const int swz = li & 7;

  const u16* qrow = qws + ((size_t)pair * SEQ + qbase + li) * DP;
  const short8 qf0 = *(const short8*)(qrow + quad * 8);
  const short8 qf1 = *(const short8*)(qrow + 32 + quad * 8);

  floatx4 ot[3];
#pragma unroll
  for (int dt = 0; dt < 3; dt++) ot[dt] = (floatx4)0.0f;
  float m_run = -3.0e38f, l_run = 0.0f;

  const u16* kbase = kws + (size_t)pair * SEQ * DP;
  const u16* vbase = vws + (size_t)pair * DH * SEQ;

  auto stage = [&](int kv, int pp){
#pragma unroll
    for (int rep = 0; rep < 4; rep++){
      const int cs = rep * 256 + t;
      if (cs < 512){
        const int row = cs >> 3, c4 = cs & 7;
        async16(&kbase[(size_t)(kv + row) * DP + ((c4 ^ (row & 7)) << 3)],
                &ldsK[pp][cs * 8]);
      } else if (cs < 896){
        const int cs2 = cs - 512;
        const int row = cs2 >> 3, c4 = cs2 & 7;
        async16(&vbase[(size_t)row * SEQ + kv + ((c4 ^ (row & 7)) << 3)],
                &ldsV[pp][cs2 * 8]);
      }
    }
  };

  u16* prow = ldsP + (w * 16 + li) * 72;

  stage(0, 0);
  for (int i = 0; i < 16; i++){
    const int p = i & 1;
    __syncthreads();
    if (i < 15) stage((i + 1) * 64, p ^ 1);

    floatx4 st[4];
#pragma unroll
    for (int yt = 0; yt < 4; yt++){
      const u16* krow = ldsK[p] + (yt * 16 + li) * 64;
      const short8 kf0 = *(const short8*)(krow + (((0 + quad) ^ swz) << 3));
      const short8 kf1 = *(const short8*)(krow + (((4 + quad) ^ swz) << 3));
      floatx4 z = (floatx4)0.0f;
      z = __builtin_amdgcn_mfma_f32_16x16x32_bf16(kf0, qf0, z, 0, 0, 0);
      z = __builtin_amdgcn_mfma_f32_16x16x32_bf16(kf1, qf1, z, 0, 0, 0);
      st[yt] = z;
    }

    float mx = -3.0e38f;
#pragma unroll
    for (int yt = 0; yt < 4; yt++)
#pragma unroll
      for (int r = 0; r < 4; r++) mx = fmaxf(mx, st[yt][r]);
    mx = fmaxf(mx, __shfl_xor(mx, 16, 64));
    mx = fmaxf(mx, __shfl_xor(mx, 32, 64));
    const float mnew = fmaxf(m_run, mx);
    const float alpha = __builtin_amdgcn_exp2f(m_run - mnew);
    m_run = mnew;

    float ls = 0.0f;
#pragma unroll
    for (int yt = 0; yt < 4; yt++){
      float p0 = __builtin_amdgcn_exp2f(st[yt][0] - mnew);
      float p1 = __builtin_amdgcn_exp2f(st[yt][1] - mnew);
      float p2 = __builtin_amdgcn_exp2f(st[yt][2] - mnew);
      float p3 = __builtin_amdgcn_exp2f(st[yt][3] - mnew);
      ls += (p0 + p1) + (p2 + p3);
      uint2v pk; pk[0] = packbf(p0, p1); pk[1] = packbf(p2, p3);
      *(uint2v*)&prow[yt * 16 + quad * 4] = pk;
    }
    l_run = l_run * alpha + ls;
#pragma unroll
    for (int dt = 0; dt < 3; dt++) ot[dt] *= alpha;

#pragma unroll
    for (int ks = 0; ks < 64; ks += 32){
      const short8 pb = *(const short8*)&ldsP[(w * 16 + li) * 72 + ks + quad * 8];
#pragma unroll
      for (int dt = 0; dt < 3; dt++){
        const short8 vf = *(const short8*)&ldsV[p][(dt * 16 + li) * 64 +
                                                  ((((ks >> 3) + quad) ^ swz) << 3)];
        ot[dt] = __builtin_amdgcn_mfma_f32_16x16x32_bf16(vf, pb, ot[dt], 0, 0, 0);
      }
    }
  }

  float ls = l_run;
  ls += __shfl_xor(ls, 16, 64);
  ls += __shfl_xor(ls, 32, 64);
  const float rl = __builtin_amdgcn_rcpf(ls);
  const int q = qbase + li;
#pragma unroll
  for (int dt = 0; dt < 3; dt++){
    floatx4 v = ot[dt];
    uint2v pk; pk[0] = packbf(v[0] * rl, v[1] * rl); pk[1] = packbf(v[2] * rl, v[3] * rl);
    *(uint2v*)&aT[((size_t)b * SEQ + q) * CDIM + h * DH + dt * 16 + quad * 4] = pk;
  }
}

// ---------------- Kernel 3: proj GEMM, fused W conversion; fp32 out + bias ----------------
// grid (16, 3, 8); A: W fp32 staged manually (XOR-chunk layout); B: aT bf16 via async16
__global__ __launch_bounds__(256) void proj_kernel(const float* __restrict__ W,
                                                   const u16* __restrict__ aT,
                                                   const float* __restrict__ bias,
                                                   float* __restrict__ out){
  __shared__ u16 ldsA[128 * 64];
  __shared__ u16 ldsB[64 * 64];
  const int t = threadIdx.x;
  const int w = t >> 6, l = t & 63;
  const int quad = l >> 4, li = l & 15;
  const int n0 = blockIdx.x * 64;
  const int m0 = blockIdx.y * 128;
  const int b  = blockIdx.z;

  floatx4 acc[2][4];
#pragma unroll
  for (int i = 0; i < 2; i++)
#pragma unroll
    for (int j = 0; j < 4; j++) acc[i][j] = (floatx4)0.0f;

  const u16* ab = aT + (size_t)b * SEQ * CDIM;
  const int swz = li & 7;
  const int orow = t >> 1, ohalf = (t & 1) * 32;

  float4 areg[8];
  {
    const float* ar = W + (size_t)(m0 + orow) * CDIM + ohalf;
#pragma unroll
    for (int j = 0; j < 8; j++) areg[j] = *(const float4*)(ar + j * 4);
  }

  for (int kk = 0; kk < CDIM; kk += 64){
    __syncthreads();
#pragma unroll
    for (int j = 0; j < 4; j++){
      uint4v v;
      v[0] = packbf(areg[2*j].x,   areg[2*j].y);
      v[1] = packbf(areg[2*j].z,   areg[2*j].w);
      v[2] = packbf(areg[2*j+1].x, areg[2*j+1].y);
      v[3] = packbf(areg[2*j+1].z, areg[2*j+1].w);
      const int chunk = (((t & 1) * 4 + j) ^ (orow & 7));
      *(uint4v*)&ldsA[orow * 64 + chunk * 8] = v;
    }
#pragma unroll
    for (int rep = 0; rep < 2; rep++){
      const int cs = rep * 256 + t;
      const int row = cs >> 3, c4 = cs & 7;
      async16(&ab[(size_t)(n0 + row) * CDIM + kk + ((c4 ^ (row & 7)) << 3)], &ldsB[cs * 8]);
    }
    __syncthreads();

    if (kk + 64 < CDIM){
      const float* ar = W + (size_t)(m0 + orow) * CDIM + kk + 64 + ohalf;
#pragma unroll
      for (int j = 0; j < 8; j++) areg[j] = *(const float4*)(ar + j * 4);
    }

#pragma unroll
    for (int kc = 0; kc < 2; kc++){
      const int rc = ((kc * 4 + quad) ^ swz) << 3;
      short8 af[2], bf[4];
#pragma unroll
      for (int i = 0; i < 2; i++)
        af[i] = *(const short8*)&ldsA[(w * 32 + i * 16 + li) * 64 + rc];
#pragma unroll
      for (int j = 0; j < 4; j++)
        bf[j] = *(const short8*)&ldsB[(j * 16 + li) * 64 + rc];
#pragma unroll
      for (int i = 0; i < 2; i++)
#pragma unroll
        for (int j = 0; j < 4; j++)
          acc[i][j] = __builtin_amdgcn_mfma_f32_16x16x32_bf16(af[i], bf[j], acc[i][j], 0, 0, 0);
    }
  }

#pragma unroll
  for (int i = 0; i < 2; i++){
    const int o0 = m0 + w * 32 + i * 16 + quad * 4;
    float bs[4];
#pragma unroll
    for (int r = 0; r < 4; r++) bs[r] = bias[o0 + r];
#pragma unroll
    for (int j = 0; j < 4; j++){
      const int s = n0 + j * 16 + li;
#pragma unroll
      for (int r = 0; r < 4; r++)
        out[((size_t)b * CDIM + o0 + r) * SEQ + s] = acc[i][j][r] + bs[r];
    }
  }
}

extern "C" void kernel_launch(void* const* d_in, const int* in_sizes, int n_in,
                              void* d_out, int out_size, void* d_ws, size_t ws_size,
                              hipStream_t stream) {
  const float* x      = (const float*)d_in[0];
  const float* w_qkv  = (const float*)d_in[1];
  const float* w_proj = (const float*)d_in[2];
  const float* b_proj = (const float*)d_in[3];
  float* out = (float*)d_out;

  char* ws = (char*)d_ws;
  const size_t SZX = (size_t)NB * SEQ * CDIM * sizeof(u16);       // 6 MB (aT)
  const size_t SZQ = (size_t)NB * NH * SEQ * DP * sizeof(u16);    // 8 MB (padded Q/K)
  u16* aT  = (u16*)(ws);
  u16* qws = (u16*)(ws + SZX);
  u16* kws = (u16*)(ws + SZX + SZQ);
  u16* vws = (u16*)(ws + SZX + 2 * SZQ);

  qkv_kernel<<<dim3(16, 9, 8), 256, 0, stream>>>(w_qkv, x, qws, kws, vws);
  attn_kernel<<<dim3(1024), 256, 0, stream>>>(qws, kws, vws, aT);
  proj_kernel<<<dim3(16, 3, 8), 256, 0, stream>>>(w_proj, aT, b_proj, out);
}